// Round 12
// baseline (527.965 us; speedup 1.0000x reference)
//
#include <hip/hip_runtime.h>

// out[b,s,j] = sum_k x[b,s,k] * w_concat[inv_perm[j], k] + bias[j]
// INT8 path: weights exact in i8; x per-token quantized (sx = absmax/127).
// Round 11: BIG per-wave tile. 4 waves/block (2x2), each wave computes
// 128x128 (acc = 256 VGPR, 1 wave/SIMD). Cross-wave LDS redundancy drops
// A:4x+B:2x -> 2x+2x (192->128 KB per K-tile): LDS-read:MFMA ratio 88%->59%.
// LDS geometry/swizzle identical to round 6 (measured conflict-free).

#define M_TOK 16384
#define N_O   4096
#define K_IN  4096
#define N8F   2048
#define NT    (K_IN / 128)   // 32 K-tiles of BK=128 i8 (128 B/row)

typedef __attribute__((ext_vector_type(4))) int i32x4;

__device__ __forceinline__ void gl_lds16(const void* g, void* l) {
  __builtin_amdgcn_global_load_lds(
      (const __attribute__((address_space(1))) unsigned int*)g,
      (__attribute__((address_space(3))) unsigned int*)l, 16, 0, 0);
}

__device__ __forceinline__ int clampq(float f) {
  int q = (int)rintf(f);
  return q > 127 ? 127 : (q < -127 ? -127 : q);
}

// ---- fused prep: blocks [0,N_O) pack weights to i8; blocks [N_O, N_O+M_TOK)
// ---- quantize one token each (absmax -> sx, xq). Row-major i8, 4096 B rows.
__global__ void prep_kernel(const float* __restrict__ x,
                            const int4* __restrict__ q8, const float* __restrict__ s8,
                            const int4* __restrict__ q4, const float* __restrict__ s4,
                            const int* __restrict__ inv,
                            char* __restrict__ Wq, float* __restrict__ scale,
                            float* __restrict__ sx, char* __restrict__ xq) {
  __shared__ float red[4];
  const int t = threadIdx.x;
  if (blockIdx.x < N_O) {
    const int j = blockIdx.x;
    const int c = inv[j];
    const int4* src; float s;
    if (c < N8F) { src = q8 + (size_t)c * (K_IN / 4);         s = s8[c]; }
    else         { src = q4 + (size_t)(c - N8F) * (K_IN / 4); s = s4[c - N8F]; }
    if (t == 0) scale[j] = s;
    unsigned dw[4];
#pragma unroll
    for (int i = 0; i < 4; ++i) {
      int4 v = src[t * 4 + i];
      dw[i] = (v.x & 255) | ((v.y & 255) << 8) | ((v.z & 255) << 16)
            | ((unsigned)(v.w & 255) << 24);
    }
    *(uint4*)(Wq + (size_t)j * K_IN + t * 16) = make_uint4(dw[0], dw[1], dw[2], dw[3]);
  } else {
    const int T = blockIdx.x - N_O;
    const float4* xr = (const float4*)(x + (size_t)T * K_IN);
    float4 v[4];
    float m = 0.f;
#pragma unroll
    for (int i = 0; i < 4; ++i) {
      v[i] = xr[t * 4 + i];
      m = fmaxf(m, fmaxf(fmaxf(fabsf(v[i].x), fabsf(v[i].y)),
                         fmaxf(fabsf(v[i].z), fabsf(v[i].w))));
    }
#pragma unroll
    for (int o = 32; o; o >>= 1) m = fmaxf(m, __shfl_xor(m, o));
    if ((t & 63) == 0) red[t >> 6] = m;
    __syncthreads();
    m = fmaxf(fmaxf(red[0], red[1]), fmaxf(red[2], red[3]));
    const float rq = m > 0.f ? 127.f / m : 0.f;
    if (t == 0) sx[T] = m * (1.f / 127.f);
    unsigned dw[4];
#pragma unroll
    for (int i = 0; i < 4; ++i) {
      int a0 = clampq(v[i].x * rq), a1 = clampq(v[i].y * rq);
      int a2 = clampq(v[i].z * rq), a3 = clampq(v[i].w * rq);
      dw[i] = (a0 & 255) | ((a1 & 255) << 8) | ((a2 & 255) << 16)
            | ((unsigned)(a3 & 255) << 24);
    }
    *(uint4*)(xq + (size_t)T * K_IN + t * 16) = make_uint4(dw[0], dw[1], dw[2], dw[3]);
  }
}

// ================= 256x256 i8 GEMM, BK=128, 4 waves of 128x128 =================
// LDS map (bytes): buf*65536 + { A: half*16384 | B: 32768 + half*16384 }
// half = 128 rows x 128 B; swizzle: phys_colbyte = logical ^ ((row&7)<<4)
__global__ __launch_bounds__(256, 1)
void gemm_i8(const char* __restrict__ xq, const char* __restrict__ Wq,
             const float* __restrict__ sx, const float* __restrict__ scale,
             const float* __restrict__ bias, float* __restrict__ out) {
  __shared__ __align__(16) char sm[131072];
  const int t = threadIdx.x;
  const int w = t >> 6, l = t & 63;
  const int wr = w >> 1, wc = w & 1;          // 2M x 2N waves, 128x128 each
  const int bm = blockIdx.x >> 4, bn = blockIdx.x & 15;
  const int row0 = bm * 256, col0 = bn * 256;

  // --- staging: per-lane pre-swizzled global source (rule #21) ---
  // each gl_lds covers 8 rows (64 lanes x 16B, 128B rows); wave w stages rows
  // w*32..w*32+31 of each 128-row half: 4 issues/half, 8 per operand, 16 total.
  const int srow = l >> 3;                              // row within 8-row group
  const int schunk = ((l & 7) ^ srow) * 16;             // inverse-swizzled 16B chunk
  const char* aG = xq + (size_t)(row0 + w * 32 + srow) * K_IN + schunk;
  const char* bG = Wq + (size_t)(col0 + w * 32 + srow) * K_IN + schunk;
  char* aL0 = sm + w * 4096;                            // + buf*65536 + h*16384
  char* bL0 = sm + 32768 + w * 4096;

  auto stage = [&](int buf, int kt) {
    const int o = kt << 7;
    char* aD = aL0 + buf * 65536;
    char* bD = bL0 + buf * 65536;
#pragma unroll
    for (int i = 0; i < 4; ++i) {               // A h0 rows w*32+8i
      gl_lds16(aG + (size_t)(8 * i) * K_IN + o, aD + i * 1024);
      gl_lds16(aG + (size_t)(128 + 8 * i) * K_IN + o, aD + 16384 + i * 1024);
      gl_lds16(bG + (size_t)(8 * i) * K_IN + o, bD + i * 1024);
      gl_lds16(bG + (size_t)(128 + 8 * i) * K_IN + o, bD + 16384 + i * 1024);
    }
  };

  // --- fragment-read base offsets (swizzled) ---
  const int lrow128 = (l & 15) * 128;
  const int cb0 = (((l >> 4) << 4) ^ ((l & 7) << 4));   // kk=0 colbyte; kk=1: ^64
  const char* rA0  = sm + wr * 16384 + lrow128 + cb0;         // + m*2048 (m 0..7)
  const char* rA0x = sm + wr * 16384 + lrow128 + (cb0 ^ 64);
  const char* rB0  = sm + 32768 + wc * 16384 + lrow128 + cb0; // + n*2048 (n 0..7)
  const char* rB0x = sm + 32768 + wc * 16384 + lrow128 + (cb0 ^ 64);

  i32x4 acc[8][8];
#pragma unroll
  for (int m = 0; m < 8; ++m)
#pragma unroll
    for (int n = 0; n < 8; ++n) acc[m][n] = (i32x4){0, 0, 0, 0};

  // --- prologue ---
  stage(0, 0);
  __syncthreads();

  for (int kt2 = 0; kt2 < NT; kt2 += 2) {
#pragma unroll
    for (int half = 0; half < 2; ++half) {              // compile-time parity
      const int kt = kt2 + half;
      const int cur = half;
      if (kt + 1 < NT) stage(cur ^ 1, kt + 1);

      // kk = 0
      {
        const char* rA = rA0 + cur * 65536;
        const char* rB = rB0 + cur * 65536;
        i32x4 b[8];
#pragma unroll
        for (int n = 0; n < 8; ++n) b[n] = *(const i32x4*)(rB + n * 2048);
#pragma unroll
        for (int mp = 0; mp < 4; ++mp) {
          i32x4 a0 = *(const i32x4*)(rA + (2 * mp) * 2048);
          i32x4 a1 = *(const i32x4*)(rA + (2 * mp + 1) * 2048);
#pragma unroll
          for (int n = 0; n < 8; ++n)
            acc[2 * mp][n] = __builtin_amdgcn_mfma_i32_16x16x64_i8(a0, b[n],
                                                acc[2 * mp][n], 0, 0, 0);
#pragma unroll
          for (int n = 0; n < 8; ++n)
            acc[2 * mp + 1][n] = __builtin_amdgcn_mfma_i32_16x16x64_i8(a1, b[n],
                                                acc[2 * mp + 1][n], 0, 0, 0);
        }
      }
      // kk = 1
      {
        const char* rA = rA0x + cur * 65536;
        const char* rB = rB0x + cur * 65536;
        i32x4 b[8];
#pragma unroll
        for (int n = 0; n < 8; ++n) b[n] = *(const i32x4*)(rB + n * 2048);
#pragma unroll
        for (int mp = 0; mp < 4; ++mp) {
          i32x4 a0 = *(const i32x4*)(rA + (2 * mp) * 2048);
          i32x4 a1 = *(const i32x4*)(rA + (2 * mp + 1) * 2048);
#pragma unroll
          for (int n = 0; n < 8; ++n)
            acc[2 * mp][n] = __builtin_amdgcn_mfma_i32_16x16x64_i8(a0, b[n],
                                                acc[2 * mp][n], 0, 0, 0);
#pragma unroll
          for (int n = 0; n < 8; ++n)
            acc[2 * mp + 1][n] = __builtin_amdgcn_mfma_i32_16x16x64_i8(a1, b[n],
                                                acc[2 * mp + 1][n], 0, 0, 0);
        }
      }
      __syncthreads();   // drains my ds_reads + gl_lds writes, then barrier
    }
  }

  // ---- epilogue: C/D col=lane&15, row=(lane>>4)*4+i ; out = acc*sx[r]*sc + bias
  const int orow0 = row0 + wr * 128 + ((l >> 4) << 2);
  const int ocol0 = col0 + wc * 128 + (l & 15);
#pragma unroll
  for (int n = 0; n < 8; ++n) {
    const int col = ocol0 + n * 16;
    const float sc = scale[col];
    const float bi = bias[col];
#pragma unroll
    for (int m = 0; m < 8; ++m) {
      const int r = orow0 + m * 16;
      const float4 sxv = *(const float4*)(sx + r);
      out[(size_t)(r + 0) * N_O + col] = (float)acc[m][n][0] * (sxv.x * sc) + bi;
      out[(size_t)(r + 1) * N_O + col] = (float)acc[m][n][1] * (sxv.y * sc) + bi;
      out[(size_t)(r + 2) * N_O + col] = (float)acc[m][n][2] * (sxv.z * sc) + bi;
      out[(size_t)(r + 3) * N_O + col] = (float)acc[m][n][3] * (sxv.w * sc) + bi;
    }
  }
}

extern "C" void kernel_launch(void* const* d_in, const int* in_sizes, int n_in,
                              void* d_out, int out_size, void* d_ws, size_t ws_size,
                              hipStream_t stream) {
  const float* x    = (const float*)d_in[0];
  const int*   q8   = (const int*)d_in[1];
  const float* s8   = (const float*)d_in[2];
  const int*   q4   = (const int*)d_in[3];
  const float* s4   = (const float*)d_in[4];
  const int*   inv  = (const int*)d_in[5];
  const float* bias = (const float*)d_in[6];
  float* out = (float*)d_out;

  // ws layout: Wq (16 MiB) | scale (16 KiB) | sx (64 KiB) | xq (64 MiB)
  char* ws = (char*)d_ws;
  char*  Wq    = ws;
  float* scale = (float*)(ws + (size_t)N_O * K_IN);
  float* sx    = (float*)(ws + (size_t)N_O * K_IN + 65536);
  char*  xq    = ws + (size_t)N_O * K_IN + 65536 + 65536;

  prep_kernel<<<N_O + M_TOK, 256, 0, stream>>>(x, (const int4*)q8, s8,
                                               (const int4*)q4, s4, inv,
                                               Wq, scale, sx, xq);
  gemm_i8<<<(M_TOK / 256) * (N_O / 256), 256, 0, stream>>>(xq, Wq, sx, scale,
                                                           bias, out);
}

// Round 13
// 401.296 us; speedup vs baseline: 1.3156x; 1.3156x over previous
//
#include <hip/hip_runtime.h>

// out[b,s,j] = sum_k x[b,s,k] * w_concat[inv_perm[j], k] + bias[j]
// INT8 path: weights exact in i8; x per-token quantized (sx = absmax/127).
// Round 12: r6 geometry (256x256, BK=128, 8 waves 2Mx4N of 128x64) with
//  (a) mfma_i32_32x32x32_i8 (same LDS bytes, ~11% faster matrix floor, half
//      the MFMA instruction count),
//  (b) 2 merged phases/K-tile (16-MFMA clusters, acc reuse distance 4),
//      5 barriers/tile, same staging rotation + counted vmcnt(6) (re-proven).

#define M_TOK 16384
#define N_O   4096
#define K_IN  4096
#define N8F   2048
#define NT    (K_IN / 128)   // 32 K-tiles of BK=128 i8 (128 B/row)

typedef __attribute__((ext_vector_type(4)))  int i32x4;
typedef __attribute__((ext_vector_type(16))) int i32x16;

__device__ __forceinline__ void gl_lds16(const void* g, void* l) {
  __builtin_amdgcn_global_load_lds(
      (const __attribute__((address_space(1))) unsigned int*)g,
      (__attribute__((address_space(3))) unsigned int*)l, 16, 0, 0);
}

__device__ __forceinline__ int clampq(float f) {
  int q = (int)rintf(f);
  return q > 127 ? 127 : (q < -127 ? -127 : q);
}

// ---- fused prep: blocks [0,N_O) pack weights to i8; blocks [N_O, N_O+M_TOK)
// ---- quantize one token each (absmax -> sx, xq). Row-major i8, 4096 B rows.
__global__ void prep_kernel(const float* __restrict__ x,
                            const int4* __restrict__ q8, const float* __restrict__ s8,
                            const int4* __restrict__ q4, const float* __restrict__ s4,
                            const int* __restrict__ inv,
                            char* __restrict__ Wq, float* __restrict__ scale,
                            float* __restrict__ sx, char* __restrict__ xq) {
  __shared__ float red[4];
  const int t = threadIdx.x;
  if (blockIdx.x < N_O) {
    const int j = blockIdx.x;
    const int c = inv[j];
    const int4* src; float s;
    if (c < N8F) { src = q8 + (size_t)c * (K_IN / 4);         s = s8[c]; }
    else         { src = q4 + (size_t)(c - N8F) * (K_IN / 4); s = s4[c - N8F]; }
    if (t == 0) scale[j] = s;
    unsigned dw[4];
#pragma unroll
    for (int i = 0; i < 4; ++i) {
      int4 v = src[t * 4 + i];
      dw[i] = (v.x & 255) | ((v.y & 255) << 8) | ((v.z & 255) << 16)
            | ((unsigned)(v.w & 255) << 24);
    }
    *(uint4*)(Wq + (size_t)j * K_IN + t * 16) = make_uint4(dw[0], dw[1], dw[2], dw[3]);
  } else {
    const int T = blockIdx.x - N_O;
    const float4* xr = (const float4*)(x + (size_t)T * K_IN);
    float4 v[4];
    float m = 0.f;
#pragma unroll
    for (int i = 0; i < 4; ++i) {
      v[i] = xr[t * 4 + i];
      m = fmaxf(m, fmaxf(fmaxf(fabsf(v[i].x), fabsf(v[i].y)),
                         fmaxf(fabsf(v[i].z), fabsf(v[i].w))));
    }
#pragma unroll
    for (int o = 32; o; o >>= 1) m = fmaxf(m, __shfl_xor(m, o));
    if ((t & 63) == 0) red[t >> 6] = m;
    __syncthreads();
    m = fmaxf(fmaxf(red[0], red[1]), fmaxf(red[2], red[3]));
    const float rq = m > 0.f ? 127.f / m : 0.f;
    if (t == 0) sx[T] = m * (1.f / 127.f);
    unsigned dw[4];
#pragma unroll
    for (int i = 0; i < 4; ++i) {
      int a0 = clampq(v[i].x * rq), a1 = clampq(v[i].y * rq);
      int a2 = clampq(v[i].z * rq), a3 = clampq(v[i].w * rq);
      dw[i] = (a0 & 255) | ((a1 & 255) << 8) | ((a2 & 255) << 16)
            | ((unsigned)(a3 & 255) << 24);
    }
    *(uint4*)(xq + (size_t)T * K_IN + t * 16) = make_uint4(dw[0], dw[1], dw[2], dw[3]);
  }
}

// ================= 256x256 i8 GEMM, BK=128, 32x32x32 MFMA, 2 phases ==============
// LDS map (bytes): buf*65536 + { A: half*16384 | B: 32768 + half*16384 }
// half = 128 rows x 128 B; swizzle: phys_colbyte = logical ^ ((row&7)<<4)
__global__ __launch_bounds__(512, 2)
void gemm_i8(const char* __restrict__ xq, const char* __restrict__ Wq,
             const float* __restrict__ sx, const float* __restrict__ scale,
             const float* __restrict__ bias, float* __restrict__ out) {
  __shared__ __align__(16) char sm[131072];
  const int t = threadIdx.x;
  const int w = t >> 6, l = t & 63;
  const int wr = w >> 2, wc = w & 3;          // 2M x 4N waves, 128x64 each
  const int bm = blockIdx.x >> 4, bn = blockIdx.x & 15;
  const int row0 = bm * 256, col0 = bn * 256;

  // --- staging: per-lane pre-swizzled global source (rule #21), as r6 ---
  const int srow = l >> 3;
  const int schunk = ((l & 7) ^ srow) * 16;
  const char* aG = xq + (size_t)(row0 + w * 16 + srow) * K_IN + schunk;
  const char* bG = Wq + (size_t)(col0 + w * 16 + srow) * K_IN + schunk;
  char* aL0 = sm + w * 2048;                  // + buf*65536 + h*16384
  char* bL0 = sm + 32768 + w * 2048;

  auto stageA = [&](int buf, int kt, int h) {
    const char* g = aG + (size_t)h * (128 * K_IN) + (size_t)kt * 128;
    char* p = aL0 + buf * 65536 + h * 16384;
    gl_lds16(g, p);
    gl_lds16(g + 8 * K_IN, p + 1024);
  };
  auto stageB = [&](int buf, int kt, int h) {
    const char* g = bG + (size_t)h * (128 * K_IN) + (size_t)kt * 128;
    char* p = bL0 + buf * 65536 + h * 16384;
    gl_lds16(g, p);
    gl_lds16(g + 8 * K_IN, p + 1024);
  };

  // --- 32x32 fragment read offsets: row=l&31, k-chunk c: phys=(c<<5)^x0 ---
  const int lrow = (l & 31) * 128;
  const int x0 = (((l >> 5) << 4) ^ ((l & 7) << 4));
  int off[4];
#pragma unroll
  for (int c = 0; c < 4; ++c) off[c] = ((c << 5) ^ x0);
  // A: + wr*16384 + m*4096 ; B: 32768 + (wc>>1)*16384 + (wc&1)*8192 + n*4096
  const char* rAb = sm + wr * 16384 + lrow;
  const char* rBb = sm + 32768 + (wc >> 1) * 16384 + (wc & 1) * 8192 + lrow;

  i32x16 acc[4][2];
#pragma unroll
  for (int m = 0; m < 4; ++m)
#pragma unroll
    for (int n = 0; n < 2; ++n)
#pragma unroll
      for (int e = 0; e < 16; ++e) acc[m][n][e] = 0;

  // --- prologue: tile0 full (8) then tile1 {B0,B1,A0} (6); vmcnt(6) ---
  stageA(0, 0, 0); stageA(0, 0, 1); stageB(0, 0, 0); stageB(0, 0, 1);
  stageB(1, 1, 0); stageB(1, 1, 1); stageA(1, 1, 0);
  asm volatile("s_waitcnt vmcnt(6)" ::: "memory");
  __builtin_amdgcn_s_barrier();

  i32x4 bfr[2][4], afr[2][4];

  for (int kt = 0; kt < NT; ++kt) {
    const int cur = kt & 1;
    const char* rA = rAb + cur * 65536;
    const char* rB = rBb + cur * 65536;

    // ==== P1: read all B (8) + A m0,m1 (8); stage A(kt+1)h1 -> buf^1 ====
#pragma unroll
    for (int n = 0; n < 2; ++n)
#pragma unroll
      for (int c = 0; c < 4; ++c)
        bfr[n][c] = *(const i32x4*)(rB + n * 4096 + off[c]);
#pragma unroll
    for (int m = 0; m < 2; ++m)
#pragma unroll
      for (int c = 0; c < 4; ++c)
        afr[m][c] = *(const i32x4*)(rA + m * 4096 + off[c]);
    if (kt + 1 < NT) stageA(cur ^ 1, kt + 1, 1);
    __builtin_amdgcn_s_barrier();
    asm volatile("s_waitcnt lgkmcnt(0)" ::: "memory");
    __builtin_amdgcn_sched_barrier(0);
    __builtin_amdgcn_s_setprio(1);
#pragma unroll
    for (int c = 0; c < 4; ++c)
#pragma unroll
      for (int m = 0; m < 2; ++m)
#pragma unroll
        for (int n = 0; n < 2; ++n)
          acc[m][n] = __builtin_amdgcn_mfma_i32_32x32x32_i8(afr[m][c], bfr[n][c],
                                                            acc[m][n], 0, 0, 0);
    __builtin_amdgcn_s_setprio(0);
    __builtin_amdgcn_s_barrier();

    // ==== P2: read A m2,m3 (8); stage B(kt+2) -> cur (B free since P1 end) ====
#pragma unroll
    for (int m = 0; m < 2; ++m)
#pragma unroll
      for (int c = 0; c < 4; ++c)
        afr[m][c] = *(const i32x4*)(rA + (2 + m) * 4096 + off[c]);
    if (kt + 2 < NT) { stageB(cur, kt + 2, 0); stageB(cur, kt + 2, 1); }
    __builtin_amdgcn_s_barrier();
    asm volatile("s_waitcnt lgkmcnt(0)" ::: "memory");
    __builtin_amdgcn_sched_barrier(0);
    __builtin_amdgcn_s_setprio(1);
#pragma unroll
    for (int c = 0; c < 4; ++c)
#pragma unroll
      for (int m = 0; m < 2; ++m)
#pragma unroll
        for (int n = 0; n < 2; ++n)
          acc[2 + m][n] = __builtin_amdgcn_mfma_i32_32x32x32_i8(afr[m][c], bfr[n][c],
                                                                acc[2 + m][n], 0, 0, 0);
    __builtin_amdgcn_s_setprio(0);
    __builtin_amdgcn_s_barrier();      // all waves past lgkm -> A-cur free

    // ==== stage A(kt+2)h0 -> cur; counted vmcnt (drains exactly tile kt+1) ====
    if (kt + 2 < NT) {
      stageA(cur, kt + 2, 0);
      asm volatile("s_waitcnt vmcnt(6)" ::: "memory");
    } else {
      asm volatile("s_waitcnt vmcnt(0)" ::: "memory");
    }
    __builtin_amdgcn_s_barrier();
  }

  // ---- epilogue: 32x32 C/D: col=lane&31, row=(reg&3)+8*(reg>>2)+4*(lane>>5) ----
  const int ocol0 = col0 + wc * 64 + (l & 31);
  const int orow0 = row0 + wr * 128 + 4 * (l >> 5);
#pragma unroll
  for (int n = 0; n < 2; ++n) {
    const int col = ocol0 + n * 32;
    const float sc = scale[col];
    const float bi = bias[col];
#pragma unroll
    for (int m = 0; m < 4; ++m) {
      const int rb = orow0 + m * 32;
#pragma unroll
      for (int g = 0; g < 4; ++g) {
        const int r = rb + 8 * g;
        const float4 sxv = *(const float4*)(sx + r);
        out[(size_t)(r + 0) * N_O + col] = (float)acc[m][n][4 * g + 0] * (sxv.x * sc) + bi;
        out[(size_t)(r + 1) * N_O + col] = (float)acc[m][n][4 * g + 1] * (sxv.y * sc) + bi;
        out[(size_t)(r + 2) * N_O + col] = (float)acc[m][n][4 * g + 2] * (sxv.z * sc) + bi;
        out[(size_t)(r + 3) * N_O + col] = (float)acc[m][n][4 * g + 3] * (sxv.w * sc) + bi;
      }
    }
  }
}

extern "C" void kernel_launch(void* const* d_in, const int* in_sizes, int n_in,
                              void* d_out, int out_size, void* d_ws, size_t ws_size,
                              hipStream_t stream) {
  const float* x    = (const float*)d_in[0];
  const int*   q8   = (const int*)d_in[1];
  const float* s8   = (const float*)d_in[2];
  const int*   q4   = (const int*)d_in[3];
  const float* s4   = (const float*)d_in[4];
  const int*   inv  = (const int*)d_in[5];
  const float* bias = (const float*)d_in[6];
  float* out = (float*)d_out;

  // ws layout: Wq (16 MiB) | scale (16 KiB) | sx (64 KiB) | xq (64 MiB)
  char* ws = (char*)d_ws;
  char*  Wq    = ws;
  float* scale = (float*)(ws + (size_t)N_O * K_IN);
  float* sx    = (float*)(ws + (size_t)N_O * K_IN + 65536);
  char*  xq    = ws + (size_t)N_O * K_IN + 65536 + 65536;

  prep_kernel<<<N_O + M_TOK, 256, 0, stream>>>(x, (const int4*)q8, s8,
                                               (const int4*)q4, s4, inv,
                                               Wq, scale, sx, xq);
  gemm_i8<<<(M_TOK / 256) * (N_O / 256), 512, 0, stream>>>(xq, Wq, sx, scale,
                                                           bias, out);
}

// Round 14
// 376.003 us; speedup vs baseline: 1.4041x; 1.0673x over previous
//
#include <hip/hip_runtime.h>

// out[b,s,j] = sum_k x[b,s,k] * w_concat[inv_perm[j], k] + bias[j]
// INT8 path: weights exact in i8; x per-token quantized (sx = absmax/127).
// FINAL/BEST (round-6 structure, best measured: gemm 296.7us, total 374.6us):
// i8 twin of the verified 4-phase 256x256 schedule. BK=128 i8 (128B rows),
// 8 waves (2Mx4N of 128x64), 2 barriers + counted vmcnt(6) per K-tile,
// st-swizzled LDS (phys_colbyte = logical ^ ((row&7)<<4)) via pre-swizzled
// global_load_lds source, setprio around MFMA clusters.
// Plateau analysis: per K-tile per CU, MFMA ~2613 cyc and LDS-read ~2300 cyc;
// eight schedule/occupancy/fragment variants (r4-r12) all fail to overlap the
// two pipes (measured ~= sum), bracketing this decomposition's plain-HIP
// ceiling at ~296us for the GEMM.

#define M_TOK 16384
#define N_O   4096
#define K_IN  4096
#define N8F   2048
#define NT    (K_IN / 128)   // 32 K-tiles of BK=128 i8 (128 B/row)

typedef __attribute__((ext_vector_type(4))) int i32x4;

__device__ __forceinline__ void gl_lds16(const void* g, void* l) {
  __builtin_amdgcn_global_load_lds(
      (const __attribute__((address_space(1))) unsigned int*)g,
      (__attribute__((address_space(3))) unsigned int*)l, 16, 0, 0);
}

__device__ __forceinline__ int clampq(float f) {
  int q = (int)rintf(f);
  return q > 127 ? 127 : (q < -127 ? -127 : q);
}

// ---- fused prep: blocks [0,N_O) pack weights to i8; blocks [N_O, N_O+M_TOK)
// ---- quantize one token each (absmax -> sx, xq). Row-major i8, 4096 B rows.
__global__ void prep_kernel(const float* __restrict__ x,
                            const int4* __restrict__ q8, const float* __restrict__ s8,
                            const int4* __restrict__ q4, const float* __restrict__ s4,
                            const int* __restrict__ inv,
                            char* __restrict__ Wq, float* __restrict__ scale,
                            float* __restrict__ sx, char* __restrict__ xq) {
  __shared__ float red[4];
  const int t = threadIdx.x;
  if (blockIdx.x < N_O) {
    const int j = blockIdx.x;
    const int c = inv[j];
    const int4* src; float s;
    if (c < N8F) { src = q8 + (size_t)c * (K_IN / 4);         s = s8[c]; }
    else         { src = q4 + (size_t)(c - N8F) * (K_IN / 4); s = s4[c - N8F]; }
    if (t == 0) scale[j] = s;
    unsigned dw[4];
#pragma unroll
    for (int i = 0; i < 4; ++i) {
      int4 v = src[t * 4 + i];
      dw[i] = (v.x & 255) | ((v.y & 255) << 8) | ((v.z & 255) << 16)
            | ((unsigned)(v.w & 255) << 24);
    }
    *(uint4*)(Wq + (size_t)j * K_IN + t * 16) = make_uint4(dw[0], dw[1], dw[2], dw[3]);
  } else {
    const int T = blockIdx.x - N_O;
    const float4* xr = (const float4*)(x + (size_t)T * K_IN);
    float4 v[4];
    float m = 0.f;
#pragma unroll
    for (int i = 0; i < 4; ++i) {
      v[i] = xr[t * 4 + i];
      m = fmaxf(m, fmaxf(fmaxf(fabsf(v[i].x), fabsf(v[i].y)),
                         fmaxf(fabsf(v[i].z), fabsf(v[i].w))));
    }
#pragma unroll
    for (int o = 32; o; o >>= 1) m = fmaxf(m, __shfl_xor(m, o));
    if ((t & 63) == 0) red[t >> 6] = m;
    __syncthreads();
    m = fmaxf(fmaxf(red[0], red[1]), fmaxf(red[2], red[3]));
    const float rq = m > 0.f ? 127.f / m : 0.f;
    if (t == 0) sx[T] = m * (1.f / 127.f);
    unsigned dw[4];
#pragma unroll
    for (int i = 0; i < 4; ++i) {
      int a0 = clampq(v[i].x * rq), a1 = clampq(v[i].y * rq);
      int a2 = clampq(v[i].z * rq), a3 = clampq(v[i].w * rq);
      dw[i] = (a0 & 255) | ((a1 & 255) << 8) | ((a2 & 255) << 16)
            | ((unsigned)(a3 & 255) << 24);
    }
    *(uint4*)(xq + (size_t)T * K_IN + t * 16) = make_uint4(dw[0], dw[1], dw[2], dw[3]);
  }
}

// ================= 256x256 i8 GEMM, BK=128, 4-phase schedule =================
// LDS map (bytes): buf*65536 + { A: half*16384 | B: 32768 + half*16384 }
// half = 128 rows x 128 B; swizzle: phys_colbyte = logical ^ ((row&7)<<4)
__global__ __launch_bounds__(512, 2)
void gemm_i8(const char* __restrict__ xq, const char* __restrict__ Wq,
             const float* __restrict__ sx, const float* __restrict__ scale,
             const float* __restrict__ bias, float* __restrict__ out) {
  __shared__ __align__(16) char sm[131072];
  const int t = threadIdx.x;
  const int w = t >> 6, l = t & 63;
  const int wr = w >> 2, wc = w & 3;          // 2M x 4N waves, 128x64 each
  const int bm = blockIdx.x >> 4, bn = blockIdx.x & 15;
  const int row0 = bm * 256, col0 = bn * 256;

  // --- staging: per-lane pre-swizzled global source (rule #21) ---
  const int srow = l >> 3;                              // row within 8-row group
  const int schunk = ((l & 7) ^ srow) * 16;             // inverse-swizzled 16B chunk
  const char* aG = xq + (size_t)(row0 + w * 16 + srow) * K_IN + schunk;
  const char* bG = Wq + (size_t)(col0 + w * 16 + srow) * K_IN + schunk;
  char* aL0 = sm + w * 2048;                            // + buf*65536 + h*16384
  char* bL0 = sm + 32768 + w * 2048;

  auto stageA = [&](int buf, int kt, int h) {
    const char* g = aG + (size_t)h * (128 * K_IN) + (size_t)kt * 128;
    char* p = aL0 + buf * 65536 + h * 16384;
    gl_lds16(g, p);
    gl_lds16(g + 8 * K_IN, p + 1024);
  };
  auto stageB = [&](int buf, int kt, int h) {
    const char* g = bG + (size_t)h * (128 * K_IN) + (size_t)kt * 128;
    char* p = bL0 + buf * 65536 + h * 16384;
    gl_lds16(g, p);
    gl_lds16(g + 8 * K_IN, p + 1024);
  };

  // --- fragment-read per-lane offsets (swizzled) ---
  const int lrow128 = (l & 15) * 128;
  const int cb0 = (((l >> 4) << 4) ^ ((l & 7) << 4));   // kk=0 colbyte; kk=1: ^64
  const int aWoff = wr * 16384 + lrow128;
  const int bWoff = 32768 + (wc >> 1) * 16384 + (wc & 1) * 8192 + lrow128;

  i32x4 acc[8][4];
#pragma unroll
  for (int m = 0; m < 8; ++m)
#pragma unroll
    for (int n = 0; n < 4; ++n) acc[m][n] = (i32x4){0, 0, 0, 0};

  // --- prologue: tile0 fully + tile1 {B0,B1,A0}; wait tile0 (vmcnt 14->6) ---
  stageB(0, 0, 0); stageB(0, 0, 1); stageA(0, 0, 0); stageA(0, 0, 1);
  stageB(1, 1, 0); stageB(1, 1, 1); stageA(1, 1, 0);
  asm volatile("s_waitcnt vmcnt(6)" ::: "memory");
  __builtin_amdgcn_s_barrier();

  i32x4 bfr[4][2], afr[2][2], afr2[2][2];

  for (int kt = 0; kt < NT; ++kt) {
    const int cur = kt & 1;
    const char* smA = sm + cur * 65536 + aWoff;
    const char* smB = sm + cur * 65536 + bWoff;

    // ---- phase 1: ds_read all B (8) + A mg0 (4); stage A1(kt+1) -> buf^1
#pragma unroll
    for (int n = 0; n < 4; ++n) {
      bfr[n][0] = *(const i32x4*)(smB + n * 2048 + cb0);
      bfr[n][1] = *(const i32x4*)(smB + n * 2048 + (cb0 ^ 64));
    }
#pragma unroll
    for (int m = 0; m < 2; ++m) {
      afr[m][0] = *(const i32x4*)(smA + m * 2048 + cb0);
      afr[m][1] = *(const i32x4*)(smA + m * 2048 + (cb0 ^ 64));
    }
    if (kt + 1 < NT) stageA(cur ^ 1, kt + 1, 1);
    __builtin_amdgcn_s_barrier();
    asm volatile("s_waitcnt lgkmcnt(0)" ::: "memory");
    __builtin_amdgcn_s_setprio(1);
#pragma unroll
    for (int m = 0; m < 2; ++m)
#pragma unroll
      for (int n = 0; n < 4; ++n)
#pragma unroll
        for (int kk = 0; kk < 2; ++kk)
          acc[m][n] = __builtin_amdgcn_mfma_i32_16x16x64_i8(afr[m][kk], bfr[n][kk],
                                                            acc[m][n], 0, 0, 0);
    __builtin_amdgcn_s_setprio(0);
    __builtin_amdgcn_s_barrier();

    // ---- phase 2: ds_read A mg1 (4); stage B0(kt+2) -> buf cur (region free since p1)
#pragma unroll
    for (int m = 0; m < 2; ++m) {
      afr[m][0] = *(const i32x4*)(smA + (2 + m) * 2048 + cb0);
      afr[m][1] = *(const i32x4*)(smA + (2 + m) * 2048 + (cb0 ^ 64));
    }
    if (kt + 2 < NT) stageB(cur, kt + 2, 0);
    __builtin_amdgcn_s_barrier();
    asm volatile("s_waitcnt lgkmcnt(0)" ::: "memory");
    __builtin_amdgcn_s_setprio(1);
#pragma unroll
    for (int m = 0; m < 2; ++m)
#pragma unroll
      for (int n = 0; n < 4; ++n)
#pragma unroll
        for (int kk = 0; kk < 2; ++kk)
          acc[2 + m][n] = __builtin_amdgcn_mfma_i32_16x16x64_i8(afr[m][kk], bfr[n][kk],
                                                                acc[2 + m][n], 0, 0, 0);
    __builtin_amdgcn_s_setprio(0);
    __builtin_amdgcn_s_barrier();

    // ---- phase 3: ds_read A mg2 (4) + A mg3 prefetch (4); stage B1(kt+2)
#pragma unroll
    for (int m = 0; m < 2; ++m) {
      afr[m][0]  = *(const i32x4*)(smA + (4 + m) * 2048 + cb0);
      afr[m][1]  = *(const i32x4*)(smA + (4 + m) * 2048 + (cb0 ^ 64));
      afr2[m][0] = *(const i32x4*)(smA + (6 + m) * 2048 + cb0);
      afr2[m][1] = *(const i32x4*)(smA + (6 + m) * 2048 + (cb0 ^ 64));
    }
    if (kt + 2 < NT) stageB(cur, kt + 2, 1);
    __builtin_amdgcn_s_barrier();
    asm volatile("s_waitcnt lgkmcnt(0)" ::: "memory");   // full drain: A regions reused in p4
    __builtin_amdgcn_s_setprio(1);
#pragma unroll
    for (int m = 0; m < 2; ++m)
#pragma unroll
      for (int n = 0; n < 4; ++n)
#pragma unroll
        for (int kk = 0; kk < 2; ++kk)
          acc[4 + m][n] = __builtin_amdgcn_mfma_i32_16x16x64_i8(afr[m][kk], bfr[n][kk],
                                                                acc[4 + m][n], 0, 0, 0);
    __builtin_amdgcn_s_setprio(0);
    __builtin_amdgcn_s_barrier();

    // ---- phase 4: stage A0(kt+2); counted vmcnt (drains exactly tile kt+1)
    if (kt + 2 < NT) {
      stageA(cur, kt + 2, 0);
      asm volatile("s_waitcnt vmcnt(6)" ::: "memory");
    } else {
      asm volatile("s_waitcnt vmcnt(0)" ::: "memory");
    }
    __builtin_amdgcn_s_barrier();
    __builtin_amdgcn_s_setprio(1);
#pragma unroll
    for (int m = 0; m < 2; ++m)
#pragma unroll
      for (int n = 0; n < 4; ++n)
#pragma unroll
        for (int kk = 0; kk < 2; ++kk)
          acc[6 + m][n] = __builtin_amdgcn_mfma_i32_16x16x64_i8(afr2[m][kk], bfr[n][kk],
                                                                acc[6 + m][n], 0, 0, 0);
    __builtin_amdgcn_s_setprio(0);
    __builtin_amdgcn_s_barrier();
  }

  // ---- epilogue: C/D col=lane&15, row=(lane>>4)*4+i ; out = acc*sx[r]*sc + bias
  const int orow0 = row0 + wr * 128 + ((l >> 4) << 2);
  const int ocol0 = col0 + wc * 64 + (l & 15);
#pragma unroll
  for (int n = 0; n < 4; ++n) {
    const int col = ocol0 + n * 16;
    const float sc = scale[col];
    const float bi = bias[col];
#pragma unroll
    for (int m = 0; m < 8; ++m) {
      const int r = orow0 + m * 16;
      const float4 sxv = *(const float4*)(sx + r);
      out[(size_t)(r + 0) * N_O + col] = (float)acc[m][n][0] * (sxv.x * sc) + bi;
      out[(size_t)(r + 1) * N_O + col] = (float)acc[m][n][1] * (sxv.y * sc) + bi;
      out[(size_t)(r + 2) * N_O + col] = (float)acc[m][n][2] * (sxv.z * sc) + bi;
      out[(size_t)(r + 3) * N_O + col] = (float)acc[m][n][3] * (sxv.w * sc) + bi;
    }
  }
}

extern "C" void kernel_launch(void* const* d_in, const int* in_sizes, int n_in,
                              void* d_out, int out_size, void* d_ws, size_t ws_size,
                              hipStream_t stream) {
  const float* x    = (const float*)d_in[0];
  const int*   q8   = (const int*)d_in[1];
  const float* s8   = (const float*)d_in[2];
  const int*   q4   = (const int*)d_in[3];
  const float* s4   = (const float*)d_in[4];
  const int*   inv  = (const int*)d_in[5];
  const float* bias = (const float*)d_in[6];
  float* out = (float*)d_out;

  // ws layout: Wq (16 MiB) | scale (16 KiB) | sx (64 KiB) | xq (64 MiB)
  char* ws = (char*)d_ws;
  char*  Wq    = ws;
  float* scale = (float*)(ws + (size_t)N_O * K_IN);
  float* sx    = (float*)(ws + (size_t)N_O * K_IN + 65536);
  char*  xq    = ws + (size_t)N_O * K_IN + 65536 + 65536;

  prep_kernel<<<N_O + M_TOK, 256, 0, stream>>>(x, (const int4*)q8, s8,
                                               (const int4*)q4, s4, inv,
                                               Wq, scale, sx, xq);
  gemm_i8<<<(M_TOK / 256) * (N_O / 256), 512, 0, stream>>>(xq, Wq, sx, scale,
                                                           bias, out);
}